// Round 10
// baseline (91.903 us; speedup 1.0000x reference)
//
#include <hip/hip_runtime.h>
#include <hip/hip_cooperative_groups.h>
#include <math.h>

namespace cg = cooperative_groups;

#define NB 768
#define ND 128
#define NC 12            // NB / 64 lane-chunks (mining layout)
#define APB 3            // anchors per block -> 256 blocks
#define NTH 384          // 6 waves per block
#define TL_MARGIN 1.0f
#define TL_EPS 1e-12f

// ws layout (bytes):
//   ET   @ 0x00000 : 128*768 f32 = 384 KB   (ET[k][j] = E[j][k])
//   sqp  @ 0x60000 : 1536 f32               (per-half-row partial sums of E^2)
//   psum @ 0x61800 : 768 f32
//   pcnt @ 0x62400 : 768 f32

__global__ __launch_bounds__(NTH) void triplet_all_kernel(
    const float* __restrict__ E, const int* __restrict__ L,
    float* __restrict__ ET, float* __restrict__ sqp,
    float* __restrict__ psum, float* __restrict__ pcnt,
    float* __restrict__ out)
{
    __shared__ float drow[APB][NB];        // 9 KB

    const int tid  = threadIdx.x;
    const int lane = tid & 63;
    const int wave = tid >> 6;             // 0..5
    const int bid  = blockIdx.x;

    // ---- phase 1: transpose E -> ET, sq partials (1 element per thread) ----
    {
        const int gid = bid * NTH + tid;   // 0..98303, coalesced read
        const float v = E[gid];
        const int j = gid >> 7;            // row
        const int k = gid & 127;           // col
        ET[(size_t)k * NB + j] = v;        // scattered store, fire-and-forget
        float s = v * v;                   // wave = 64 consecutive k of one row-half
        #pragma unroll
        for (int off = 32; off > 0; off >>= 1) s += __shfl_xor(s, off);
        if (lane == 0) sqp[gid >> 6] = s;  // partial for half-row (gid>>6)
    }
    cg::this_grid().sync();

    // ---- phase 2: distance + mining (R8-proven structure) ----
    int i0 = bid * APB;
    i0 = __builtin_amdgcn_readfirstlane(i0);

    // anchor rows via wave-uniform pointers -> scalar (SGPR) loads
    const float* __restrict__ A0 = E + (size_t)(i0 + 0) * ND;
    const float* __restrict__ A1 = E + (size_t)(i0 + 1) * ND;
    const float* __restrict__ A2 = E + (size_t)(i0 + 2) * ND;
    const float sqa0 = sqp[2 * i0]     + sqp[2 * i0 + 1];
    const float sqa1 = sqp[2 * i0 + 2] + sqp[2 * i0 + 3];
    const float sqa2 = sqp[2 * i0 + 4] + sqp[2 * i0 + 5];

    // distance: wave w covers j in [w*128, w*128+128), float2 per lane
    {
        const float2* __restrict__ Bp = (const float2*)ET + (wave * 64 + lane);
        float px0 = 0.f, py0 = 0.f, px1 = 0.f, py1 = 0.f, px2 = 0.f, py2 = 0.f;
        #pragma unroll 8
        for (int k = 0; k < ND; ++k) {
            float2 b = Bp[(size_t)k * 384];    // coalesced 512 B per wave-instr
            float a0 = A0[k], a1 = A1[k], a2 = A2[k];   // SGPR broadcasts
            px0 += a0 * b.x; py0 += a0 * b.y;
            px1 += a1 * b.x; py1 += a1 * b.y;
            px2 += a2 * b.x; py2 += a2 * b.y;
        }
        const int j0 = wave * 128 + lane * 2;
        const float4 sp = *(const float4*)(sqp + 2 * j0);  // partials for j0, j0+1
        const float sjx = sp.x + sp.y;
        const float sjy = sp.z + sp.w;
        float2 d;
        d.x = sqrtf(fmaxf(sqa0 + sjx - 2.f * px0, TL_EPS));
        d.y = sqrtf(fmaxf(sqa0 + sjy - 2.f * py0, TL_EPS));
        *(float2*)&drow[0][j0] = d;
        d.x = sqrtf(fmaxf(sqa1 + sjx - 2.f * px1, TL_EPS));
        d.y = sqrtf(fmaxf(sqa1 + sjy - 2.f * py1, TL_EPS));
        *(float2*)&drow[1][j0] = d;
        d.x = sqrtf(fmaxf(sqa2 + sjx - 2.f * px2, TL_EPS));
        d.y = sqrtf(fmaxf(sqa2 + sjy - 2.f * py2, TL_EPS));
        *(float2*)&drow[2][j0] = d;
    }
    __syncthreads();

    // mining: waves 0..2, wave = anchor (proven code)
    if (wave < APB) {
        const int ia = i0 + wave;
        const int li = L[ia];
        unsigned negm = 0u, posm = 0u;
        float dk[NC];
        #pragma unroll
        for (int c = 0; c < NC; ++c) {
            int j = c * 64 + lane;
            dk[c] = drow[wave][j];
            int lj = L[j];
            if (lj != li)     negm |= (1u << c);
            else if (j != ia) posm |= (1u << c);
        }

        float bv = INFINITY;
        #pragma unroll
        for (int c = 0; c < NC; ++c)
            if ((negm >> c) & 1u) bv = fminf(bv, dk[c]);
        #pragma unroll
        for (int off = 32; off > 0; off >>= 1)
            bv = fminf(bv, __shfl_xor(bv, off));
        const float hval = bv;

        float lsum = 0.f, lcnt = 0.f;
        if (isfinite(hval)) {
            #pragma unroll
            for (int c = 0; c < NC; ++c) {
                unsigned long long pm = __ballot((posm >> c) & 1u);
                while (pm) {
                    const int sl = __builtin_ctzll(pm);
                    pm &= pm - 1;
                    const float pd = __shfl(dk[c], sl);
                    float nd = hval;
                    #pragma unroll
                    for (int c2 = 0; c2 < NC; ++c2) {
                        bool pred = ((negm >> c2) & 1u) &&
                                    (dk[c2] > pd) && (dk[c2] < pd + TL_MARGIN);
                        unsigned long long m = __ballot(pred);
                        if (m) { nd = __shfl(dk[c2], __builtin_ctzll(m)); break; }
                    }
                    lsum += fmaxf(pd - nd + TL_MARGIN, 0.f);
                    lcnt += 1.f;
                }
            }
        }
        if (lane == 0) { psum[ia] = lsum; pcnt[ia] = lcnt; }
    }
    cg::this_grid().sync();

    // ---- phase 3: block 0, wave 0 finalizes ----
    if (bid == 0 && wave == 0) {
        float a = 0.f, b = 0.f;
        for (int j = lane; j < NB; j += 64) { a += psum[j]; b += pcnt[j]; }
        #pragma unroll
        for (int off = 32; off > 0; off >>= 1) {
            a += __shfl_xor(a, off);
            b += __shfl_xor(b, off);
        }
        if (lane == 0) out[0] = a / fmaxf(b, 1.f);
    }
}

extern "C" void kernel_launch(void* const* d_in, const int* in_sizes, int n_in,
                              void* d_out, int out_size, void* d_ws, size_t ws_size,
                              hipStream_t stream) {
    const float* E = (const float*)d_in[0];
    const int*   L = (const int*)d_in[1];
    char* ws = (char*)d_ws;
    float* ET   = (float*)(ws);
    float* sqp  = (float*)(ws + 0x60000);
    float* psum = (float*)(ws + 0x61800);
    float* pcnt = (float*)(ws + 0x62400);
    float* out  = (float*)d_out;

    void* args[] = {(void*)&E, (void*)&L, (void*)&ET, (void*)&sqp,
                    (void*)&psum, (void*)&pcnt, (void*)&out};
    (void)hipLaunchCooperativeKernel((const void*)triplet_all_kernel,
                                     dim3(NB / APB), dim3(NTH), args, 0, stream);
}

// Round 11
// 59.405 us; speedup vs baseline: 1.5471x; 1.5471x over previous
//
#include <hip/hip_runtime.h>
#include <math.h>

#define NB 768
#define ND 128
#define NC 12            // NB / 64 lane-chunks (mining layout)
#define APB 12           // anchors per block -> 64 blocks
#define NTH 768          // 12 waves per block
#define TL_MARGIN 1.0f
#define TL_EPS 1e-12f

// ws layout (bytes):
//   ET   @ 0x00000 : 128*768 f32 = 384 KB   (ET[k][j] = E[j][k])
//   sq   @ 0x60000 : 768 f32
//   psum @ 0x61000 : 768 f32
//   pcnt @ 0x61C00 : 768 f32

// ---- K0: transpose + sq, high-TLP (384 blocks x 256 thr) ----
__global__ __launch_bounds__(256) void transpose_sq_kernel(
    const float* __restrict__ E, float* __restrict__ ET, float* __restrict__ sq)
{
    __shared__ float part[4];
    const int b    = blockIdx.x;
    const int tid  = threadIdx.x;
    const int lane = tid & 63;
    const int wave = tid >> 6;

    const int idx = b * 256 + tid;        // global element index, coalesced read
    const float v = E[idx];
    const int j = idx >> 7;               // row
    const int k = idx & 127;              // col
    ET[(size_t)k * NB + j] = v;           // scattered store, fire-and-forget

    // wave w holds 64 consecutive k of row (2b + w/2); reduce v^2
    float s = v * v;
    #pragma unroll
    for (int off = 32; off > 0; off >>= 1) s += __shfl_xor(s, off);
    if (lane == 0) part[wave] = s;
    __syncthreads();
    if (tid == 0) {
        sq[2 * b]     = part[0] + part[1];
        sq[2 * b + 1] = part[2] + part[3];
    }
}

// ---- K1: fused distance + mining; 64 blocks x 768 thr (12 waves) ----
__global__ __launch_bounds__(NTH) void triplet_fused_kernel(
    const float* __restrict__ E, const float* __restrict__ ET,
    const float* __restrict__ sq, const int* __restrict__ L,
    float* __restrict__ psum, float* __restrict__ pcnt)
{
    __shared__ float drow[APB][NB];        // 36 KB

    const int tid  = threadIdx.x;
    const int lane = tid & 63;
    const int wave = tid >> 6;             // 0..11
    int i0 = blockIdx.x * APB;
    i0 = __builtin_amdgcn_readfirstlane(i0);   // wave-uniform -> SGPR

    // anchor norms (scalar loads)
    float sqa[APB];
    #pragma unroll
    for (int a = 0; a < APB; ++a) sqa[a] = sq[i0 + a];

    // ---- distance: wave w covers j = w*64 + lane; 12 anchors per loaded b ----
    {
        const int j = wave * 64 + lane;
        const float* __restrict__ Bcol = ET + j;
        float p[APB];
        #pragma unroll
        for (int a = 0; a < APB; ++a) p[a] = 0.f;

        #pragma unroll 16
        for (int k = 0; k < ND; ++k) {
            float b = Bcol[(size_t)k * NB];         // coalesced 256 B per wave-instr
            #pragma unroll
            for (int a = 0; a < APB; ++a)
                p[a] += E[(size_t)(i0 + a) * ND + k] * b;   // SGPR broadcast
        }
        const float sjv = sq[j];
        #pragma unroll
        for (int a = 0; a < APB; ++a)
            drow[a][j] = sqrtf(fmaxf(sqa[a] + sjv - 2.f * p[a], TL_EPS));
    }
    __syncthreads();

    // ---- mining: wave w mines anchor i0+w (proven code) ----
    {
        const int ia = i0 + wave;
        const int li = L[ia];
        unsigned negm = 0u, posm = 0u;
        float dk[NC];
        #pragma unroll
        for (int c = 0; c < NC; ++c) {
            int j = c * 64 + lane;
            dk[c] = drow[wave][j];
            int lj = L[j];
            if (lj != li)     negm |= (1u << c);
            else if (j != ia) posm |= (1u << c);
        }

        float bv = INFINITY;
        #pragma unroll
        for (int c = 0; c < NC; ++c)
            if ((negm >> c) & 1u) bv = fminf(bv, dk[c]);
        #pragma unroll
        for (int off = 32; off > 0; off >>= 1)
            bv = fminf(bv, __shfl_xor(bv, off));
        const float hval = bv;

        float lsum = 0.f, lcnt = 0.f;
        if (isfinite(hval)) {
            #pragma unroll
            for (int c = 0; c < NC; ++c) {
                unsigned long long pm = __ballot((posm >> c) & 1u);
                while (pm) {
                    const int sl = __builtin_ctzll(pm);
                    pm &= pm - 1;
                    const float pd = __shfl(dk[c], sl);
                    float nd = hval;
                    #pragma unroll
                    for (int c2 = 0; c2 < NC; ++c2) {
                        bool pred = ((negm >> c2) & 1u) &&
                                    (dk[c2] > pd) && (dk[c2] < pd + TL_MARGIN);
                        unsigned long long m = __ballot(pred);
                        if (m) { nd = __shfl(dk[c2], __builtin_ctzll(m)); break; }
                    }
                    lsum += fmaxf(pd - nd + TL_MARGIN, 0.f);
                    lcnt += 1.f;
                }
            }
        }
        if (lane == 0) { psum[ia] = lsum; pcnt[ia] = lcnt; }
    }
}

__global__ __launch_bounds__(64) void triplet_finalize_kernel(
    const float* __restrict__ psum, const float* __restrict__ pcnt,
    float* __restrict__ out)
{
    const int lane = threadIdx.x;
    float a = 0.f, b = 0.f;
    for (int j = lane; j < NB; j += 64) { a += psum[j]; b += pcnt[j]; }
    #pragma unroll
    for (int off = 32; off > 0; off >>= 1) {
        a += __shfl_xor(a, off);
        b += __shfl_xor(b, off);
    }
    if (lane == 0) out[0] = a / fmaxf(b, 1.f);
}

extern "C" void kernel_launch(void* const* d_in, const int* in_sizes, int n_in,
                              void* d_out, int out_size, void* d_ws, size_t ws_size,
                              hipStream_t stream) {
    const float* E = (const float*)d_in[0];
    const int*   L = (const int*)d_in[1];
    char* ws = (char*)d_ws;
    float* ET   = (float*)(ws);
    float* sq   = (float*)(ws + 0x60000);
    float* psum = (float*)(ws + 0x61000);
    float* pcnt = (float*)(ws + 0x61C00);
    float* out  = (float*)d_out;

    transpose_sq_kernel<<<NB * ND / 256, 256, 0, stream>>>(E, ET, sq);
    triplet_fused_kernel<<<NB / APB, NTH, 0, stream>>>(E, ET, sq, L, psum, pcnt);
    triplet_finalize_kernel<<<1, 64, 0, stream>>>(psum, pcnt, out);
}

// Round 12
// 29.345 us; speedup vs baseline: 3.1318x; 2.0243x over previous
//
#include <hip/hip_runtime.h>
#include <math.h>

#define NB 768
#define ND 128
#define NC 12            // NB / 64 lane-chunks (mining layout)
#define APB 3            // anchors per block -> 256 blocks
#define NTH 768          // 12 waves per block
#define TL_MARGIN 1.0f
#define TL_EPS 1e-12f

// ws layout (bytes):
//   ET   @ 0x00000 : 128*768 f32 = 384 KB   (ET[k][j] = E[j][k])
//   sq   @ 0x60000 : 768 f32
//   psum @ 0x61000 : 768 f32
//   pcnt @ 0x61C00 : 768 f32

// ---- K0: transpose + sq, high-TLP (384 blocks x 256 thr) ----
__global__ __launch_bounds__(256) void transpose_sq_kernel(
    const float* __restrict__ E, float* __restrict__ ET, float* __restrict__ sq)
{
    __shared__ float part[4];
    const int b    = blockIdx.x;
    const int tid  = threadIdx.x;
    const int lane = tid & 63;
    const int wave = tid >> 6;

    const int idx = b * 256 + tid;        // global element index, coalesced read
    const float v = E[idx];
    const int j = idx >> 7;               // row
    const int k = idx & 127;              // col
    ET[(size_t)k * NB + j] = v;           // scattered store, fire-and-forget

    // wave w holds 64 consecutive k of row (2b + w/2); reduce v^2
    float s = v * v;
    #pragma unroll
    for (int off = 32; off > 0; off >>= 1) s += __shfl_xor(s, off);
    if (lane == 0) part[wave] = s;
    __syncthreads();
    if (tid == 0) {
        sq[2 * b]     = part[0] + part[1];
        sq[2 * b + 1] = part[2] + part[3];
    }
}

// ---- K1: fused distance + mining; 256 blocks x 768 thr (12 waves) ----
__global__ __launch_bounds__(NTH) void triplet_fused_kernel(
    const float* __restrict__ E, const float* __restrict__ ET,
    const float* __restrict__ sq, const int* __restrict__ L,
    float* __restrict__ psum, float* __restrict__ pcnt)
{
    __shared__ float drow[APB][NB];        // 9 KB

    const int tid  = threadIdx.x;
    const int lane = tid & 63;
    const int wave = tid >> 6;             // 0..11
    int i0 = blockIdx.x * APB;
    i0 = __builtin_amdgcn_readfirstlane(i0);

    // anchor rows via wave-uniform pointers -> scalar (SGPR) loads
    const float* __restrict__ A0 = E + (size_t)(i0 + 0) * ND;
    const float* __restrict__ A1 = E + (size_t)(i0 + 1) * ND;
    const float* __restrict__ A2 = E + (size_t)(i0 + 2) * ND;
    const float sqa0 = sq[i0], sqa1 = sq[i0 + 1], sqa2 = sq[i0 + 2];

    // ---- distance: wave w covers j = w*64 + lane; one dword per lane per k ----
    {
        const int j = wave * 64 + lane;
        const float* __restrict__ Bcol = ET + j;
        float p0 = 0.f, p1 = 0.f, p2 = 0.f;
        #pragma unroll 16
        for (int k = 0; k < ND; ++k) {
            float b = Bcol[(size_t)k * NB];     // coalesced 256 B per wave-instr
            float a0 = A0[k], a1 = A1[k], a2 = A2[k];   // SGPR broadcasts
            p0 += a0 * b; p1 += a1 * b; p2 += a2 * b;
        }
        const float sjv = sq[j];
        drow[0][j] = sqrtf(fmaxf(sqa0 + sjv - 2.f * p0, TL_EPS));
        drow[1][j] = sqrtf(fmaxf(sqa1 + sjv - 2.f * p1, TL_EPS));
        drow[2][j] = sqrtf(fmaxf(sqa2 + sjv - 2.f * p2, TL_EPS));
    }
    __syncthreads();

    // ---- mining: waves 0..2, wave = anchor (proven code) ----
    if (wave < APB) {
        const int ia = i0 + wave;
        const int li = L[ia];
        unsigned negm = 0u, posm = 0u;
        float dk[NC];
        #pragma unroll
        for (int c = 0; c < NC; ++c) {
            int j = c * 64 + lane;
            dk[c] = drow[wave][j];
            int lj = L[j];
            if (lj != li)     negm |= (1u << c);
            else if (j != ia) posm |= (1u << c);
        }

        float bv = INFINITY;
        #pragma unroll
        for (int c = 0; c < NC; ++c)
            if ((negm >> c) & 1u) bv = fminf(bv, dk[c]);
        #pragma unroll
        for (int off = 32; off > 0; off >>= 1)
            bv = fminf(bv, __shfl_xor(bv, off));
        const float hval = bv;

        float lsum = 0.f, lcnt = 0.f;
        if (isfinite(hval)) {
            #pragma unroll
            for (int c = 0; c < NC; ++c) {
                unsigned long long pm = __ballot((posm >> c) & 1u);
                while (pm) {
                    const int sl = __builtin_ctzll(pm);
                    pm &= pm - 1;
                    const float pd = __shfl(dk[c], sl);
                    float nd = hval;
                    #pragma unroll
                    for (int c2 = 0; c2 < NC; ++c2) {
                        bool pred = ((negm >> c2) & 1u) &&
                                    (dk[c2] > pd) && (dk[c2] < pd + TL_MARGIN);
                        unsigned long long m = __ballot(pred);
                        if (m) { nd = __shfl(dk[c2], __builtin_ctzll(m)); break; }
                    }
                    lsum += fmaxf(pd - nd + TL_MARGIN, 0.f);
                    lcnt += 1.f;
                }
            }
        }
        if (lane == 0) { psum[ia] = lsum; pcnt[ia] = lcnt; }
    }
}

__global__ __launch_bounds__(64) void triplet_finalize_kernel(
    const float* __restrict__ psum, const float* __restrict__ pcnt,
    float* __restrict__ out)
{
    const int lane = threadIdx.x;
    float a = 0.f, b = 0.f;
    for (int j = lane; j < NB; j += 64) { a += psum[j]; b += pcnt[j]; }
    #pragma unroll
    for (int off = 32; off > 0; off >>= 1) {
        a += __shfl_xor(a, off);
        b += __shfl_xor(b, off);
    }
    if (lane == 0) out[0] = a / fmaxf(b, 1.f);
}

extern "C" void kernel_launch(void* const* d_in, const int* in_sizes, int n_in,
                              void* d_out, int out_size, void* d_ws, size_t ws_size,
                              hipStream_t stream) {
    const float* E = (const float*)d_in[0];
    const int*   L = (const int*)d_in[1];
    char* ws = (char*)d_ws;
    float* ET   = (float*)(ws);
    float* sq   = (float*)(ws + 0x60000);
    float* psum = (float*)(ws + 0x61000);
    float* pcnt = (float*)(ws + 0x61C00);
    float* out  = (float*)d_out;

    transpose_sq_kernel<<<NB * ND / 256, 256, 0, stream>>>(E, ET, sq);
    triplet_fused_kernel<<<NB / APB, NTH, 0, stream>>>(E, ET, sq, L, psum, pcnt);
    triplet_finalize_kernel<<<1, 64, 0, stream>>>(psum, pcnt, out);
}

// Round 13
// 26.989 us; speedup vs baseline: 3.4052x; 1.0873x over previous
//
#include <hip/hip_runtime.h>
#include <math.h>

#define NB 768
#define ND 128
#define NC 12            // NB / 64 lane-chunks (mining layout)
#define APB 3            // anchors per block -> 256 blocks
#define NTH 768          // 12 waves per block
#define TL_MARGIN 1.0f
#define TL_EPS 1e-12f

// ws layout (bytes):
//   ET   @ 0x00000 : 128*768 f32 = 384 KB   (ET[k][j] = E[j][k])
//   psum @ 0x60000 : 768 f32
//   pcnt @ 0x60C00 : 768 f32

// ---- K0: pure transpose, coalesced ET writes; 384 blocks x 256 thr ----
__global__ __launch_bounds__(256) void transpose_kernel(
    const float* __restrict__ E, float* __restrict__ ET)
{
    const int b   = blockIdx.x;           // 0..383
    const int tid = threadIdx.x;
    const int k   = b / 3;                // uniform per block
    const int j   = (b % 3) * 256 + tid;  // lanes consecutive j
    ET[(size_t)k * NB + j] = E[(size_t)j * ND + k];  // write: full coalesced lines
}

// ---- K1: fused distance + mining; 256 blocks x 768 thr (12 waves) ----
__global__ __launch_bounds__(NTH) void triplet_fused_kernel(
    const float* __restrict__ E, const float* __restrict__ ET,
    const int* __restrict__ L,
    float* __restrict__ psum, float* __restrict__ pcnt)
{
    __shared__ float drow[APB][NB];        // 9 KB ; holds sj - 2*dot (pre-sqa)

    const int tid  = threadIdx.x;
    const int lane = tid & 63;
    const int wave = tid >> 6;             // 0..11
    int i0 = blockIdx.x * APB;
    i0 = __builtin_amdgcn_readfirstlane(i0);

    // anchor rows via wave-uniform pointers -> scalar (SGPR) loads
    const float* __restrict__ A0 = E + (size_t)(i0 + 0) * ND;
    const float* __restrict__ A1 = E + (size_t)(i0 + 1) * ND;
    const float* __restrict__ A2 = E + (size_t)(i0 + 2) * ND;

    // mining waves (0..2) privately compute their anchor's squared norm:
    // coalesced 256B row loads + butterfly; result uniform across the wave.
    float sqa = 0.f;
    if (wave < APB) {
        const float* __restrict__ Ar = E + (size_t)(i0 + wave) * ND;
        float v0 = Ar[lane], v1 = Ar[lane + 64];
        float s = v0 * v0 + v1 * v1;
        #pragma unroll
        for (int off = 32; off > 0; off >>= 1) s += __shfl_xor(s, off);
        sqa = s;
    }

    // ---- distance: wave w covers j = w*64 + lane; sj falls out of the stream ----
    {
        const int j = wave * 64 + lane;
        const float* __restrict__ Bcol = ET + j;
        float p0 = 0.f, p1 = 0.f, p2 = 0.f, sjv = 0.f;
        #pragma unroll 16
        for (int k = 0; k < ND; ++k) {
            float b = Bcol[(size_t)k * NB];     // coalesced 256 B per wave-instr
            float a0 = A0[k], a1 = A1[k], a2 = A2[k];   // SGPR broadcasts
            sjv += b * b;
            p0 += a0 * b; p1 += a1 * b; p2 += a2 * b;
        }
        drow[0][j] = sjv - 2.f * p0;
        drow[1][j] = sjv - 2.f * p1;
        drow[2][j] = sjv - 2.f * p2;
    }
    __syncthreads();

    // ---- mining: waves 0..2, wave = anchor (proven code; sqrt at read) ----
    if (wave < APB) {
        const int ia = i0 + wave;
        const int li = L[ia];
        unsigned negm = 0u, posm = 0u;
        float dk[NC];
        #pragma unroll
        for (int c = 0; c < NC; ++c) {
            int j = c * 64 + lane;
            dk[c] = sqrtf(fmaxf(sqa + drow[wave][j], TL_EPS));
            int lj = L[j];
            if (lj != li)     negm |= (1u << c);
            else if (j != ia) posm |= (1u << c);
        }

        float bv = INFINITY;
        #pragma unroll
        for (int c = 0; c < NC; ++c)
            if ((negm >> c) & 1u) bv = fminf(bv, dk[c]);
        #pragma unroll
        for (int off = 32; off > 0; off >>= 1)
            bv = fminf(bv, __shfl_xor(bv, off));
        const float hval = bv;

        float lsum = 0.f, lcnt = 0.f;
        if (isfinite(hval)) {
            #pragma unroll
            for (int c = 0; c < NC; ++c) {
                unsigned long long pm = __ballot((posm >> c) & 1u);
                while (pm) {
                    const int sl = __builtin_ctzll(pm);
                    pm &= pm - 1;
                    const float pd = __shfl(dk[c], sl);
                    float nd = hval;
                    #pragma unroll
                    for (int c2 = 0; c2 < NC; ++c2) {
                        bool pred = ((negm >> c2) & 1u) &&
                                    (dk[c2] > pd) && (dk[c2] < pd + TL_MARGIN);
                        unsigned long long m = __ballot(pred);
                        if (m) { nd = __shfl(dk[c2], __builtin_ctzll(m)); break; }
                    }
                    lsum += fmaxf(pd - nd + TL_MARGIN, 0.f);
                    lcnt += 1.f;
                }
            }
        }
        if (lane == 0) { psum[ia] = lsum; pcnt[ia] = lcnt; }
    }
}

__global__ __launch_bounds__(64) void triplet_finalize_kernel(
    const float* __restrict__ psum, const float* __restrict__ pcnt,
    float* __restrict__ out)
{
    const int lane = threadIdx.x;
    const float4* ps4 = (const float4*)psum;
    const float4* pc4 = (const float4*)pcnt;
    float a = 0.f, b = 0.f;
    #pragma unroll
    for (int r = 0; r < 3; ++r) {          // 192 float4 per array
        float4 x = ps4[lane + r * 64];
        float4 y = pc4[lane + r * 64];
        a += x.x + x.y + x.z + x.w;
        b += y.x + y.y + y.z + y.w;
    }
    #pragma unroll
    for (int off = 32; off > 0; off >>= 1) {
        a += __shfl_xor(a, off);
        b += __shfl_xor(b, off);
    }
    if (lane == 0) out[0] = a / fmaxf(b, 1.f);
}

extern "C" void kernel_launch(void* const* d_in, const int* in_sizes, int n_in,
                              void* d_out, int out_size, void* d_ws, size_t ws_size,
                              hipStream_t stream) {
    const float* E = (const float*)d_in[0];
    const int*   L = (const int*)d_in[1];
    char* ws = (char*)d_ws;
    float* ET   = (float*)(ws);
    float* psum = (float*)(ws + 0x60000);
    float* pcnt = (float*)(ws + 0x60C00);
    float* out  = (float*)d_out;

    transpose_kernel<<<NB * ND / 256, 256, 0, stream>>>(E, ET);
    triplet_fused_kernel<<<NB / APB, NTH, 0, stream>>>(E, ET, L, psum, pcnt);
    triplet_finalize_kernel<<<1, 64, 0, stream>>>(psum, pcnt, out);
}